// Round 5
// baseline (71.047 us; speedup 1.0000x reference)
//
#include <hip/hip_runtime.h>

#define N_SAMPLES 128

// DPP ctrl encodings (gfx9/CDNA)
#define DPP_ROW_SHL1  0x101  // lane i <- lane i+1 (toward lower lanes); last lane of row invalid
#define DPP_ROW_SHR1  0x111  // lane i <- lane i-1; first lane of row invalid
#define DPP_ROW_SHR2  0x112
#define DPP_ROW_SHR4  0x114
#define DPP_ROW_SHR8  0x118
#define DPP_ROW_ROR4  0x124
#define DPP_ROW_ROR8  0x128
#define DPP_QUAD_XOR1 0xB1   // quad_perm [1,0,3,2]
#define DPP_QUAD_XOR2 0x4E   // quad_perm [2,3,0,1]

// DPP-shifted value; lanes with invalid source keep old = 1.0 (mult. identity).
template <int CTRL>
__device__ __forceinline__ float dpp_shift_id1(float src) {
    int s = __builtin_bit_cast(int, src);
    int o = __builtin_bit_cast(int, 1.0f);
    int r = __builtin_amdgcn_update_dpp(o, s, CTRL, 0xF, 0xF, false);
    return __builtin_bit_cast(float, r);
}

// Plain DPP move for all-valid patterns (quad_perm, row_ror).
template <int CTRL>
__device__ __forceinline__ float dpp_mov(float src) {
    int r = __builtin_amdgcn_mov_dpp(__builtin_bit_cast(int, src), CTRL, 0xF, 0xF, true);
    return __builtin_bit_cast(float, r);
}

// Sum across a 16-lane row entirely on the DPP pipe (all lanes get row sum).
__device__ __forceinline__ float row16_sum(float x) {
    x += dpp_mov<DPP_QUAD_XOR1>(x);
    x += dpp_mov<DPP_QUAD_XOR2>(x);
    x += dpp_mov<DPP_ROW_ROR4>(x);
    x += dpp_mov<DPP_ROW_ROR8>(x);
    return x;
}

__global__ __launch_bounds__(256) void volrender_kernel(
    const float* __restrict__ depth,
    const float* __restrict__ rgb,
    const float* __restrict__ sigma,
    float* __restrict__ out_color,
    float* __restrict__ out_depth,
    int n_rays)
{
    // 16 lanes per ray (one DPP row), 8 samples per lane.
    // 4 rays per wave, 16 rays per 256-thread block.
    const int tid = threadIdx.x;
    const int g   = tid & 15;                 // lane within the ray's row
    const int ray = blockIdx.x * 16 + (tid >> 4);
    if (ray >= n_rays) return;

    const size_t base = (size_t)ray * N_SAMPLES + g * 8;

    float4 d0 = *reinterpret_cast<const float4*>(depth + base);
    float4 d1 = *reinterpret_cast<const float4*>(depth + base + 4);
    float4 s0 = *reinterpret_cast<const float4*>(sigma + base);
    float4 s1 = *reinterpret_cast<const float4*>(sigma + base + 4);

    // neighbor's first depth via row_shl:1 (lane g <- lane g+1); g==15 unused
    float dnext = dpp_shift_id1<DPP_ROW_SHL1>(d0.x);

    float dl0 = d0.y - d0.x;
    float dl1 = d0.z - d0.y;
    float dl2 = d0.w - d0.z;
    float dl3 = d1.x - d0.w;
    float dl4 = d1.y - d1.x;
    float dl5 = d1.z - d1.y;
    float dl6 = d1.w - d1.z;
    float dl7 = (g == 15) ? 1e10f : (dnext - d1.w);

    const float EPS = 1e-10f;
    float e0 = __expf(-fmaxf(s0.x, 0.0f) * dl0);
    float e1 = __expf(-fmaxf(s0.y, 0.0f) * dl1);
    float e2 = __expf(-fmaxf(s0.z, 0.0f) * dl2);
    float e3 = __expf(-fmaxf(s0.w, 0.0f) * dl3);
    float e4 = __expf(-fmaxf(s1.x, 0.0f) * dl4);
    float e5 = __expf(-fmaxf(s1.y, 0.0f) * dl5);
    float e6 = __expf(-fmaxf(s1.z, 0.0f) * dl6);
    float e7 = __expf(-fmaxf(s1.w, 0.0f) * dl7);

    float a0 = 1.0f - e0, a1 = 1.0f - e1, a2 = 1.0f - e2, a3 = 1.0f - e3;
    float a4 = 1.0f - e4, a5 = 1.0f - e5, a6 = 1.0f - e6, a7 = 1.0f - e7;
    float t0 = e0 + EPS, t1 = e1 + EPS, t2 = e2 + EPS, t3 = e3 + EPS;
    float t4 = e4 + EPS, t5 = e5 + EPS, t6 = e6 + EPS, t7 = e7 + EPS;

    // --- row-16 exclusive multiplicative scan of per-lane product, all DPP ---
    float p = (t0 * t1) * (t2 * t3) * ((t4 * t5) * (t6 * t7));
    p *= dpp_shift_id1<DPP_ROW_SHR1>(p);
    p *= dpp_shift_id1<DPP_ROW_SHR2>(p);
    p *= dpp_shift_id1<DPP_ROW_SHR4>(p);
    p *= dpp_shift_id1<DPP_ROW_SHR8>(p);          // row-16 inclusive
    float excl = dpp_shift_id1<DPP_ROW_SHR1>(p);  // exclusive; lane0 <- 1.0

    float pre = excl;
    float w0 = a0 * pre; pre *= t0;
    float w1 = a1 * pre; pre *= t1;
    float w2 = a2 * pre; pre *= t2;
    float w3 = a3 * pre; pre *= t3;
    float w4 = a4 * pre; pre *= t4;
    float w5 = a5 * pre; pre *= t5;
    float w6 = a6 * pre; pre *= t6;
    float w7 = a7 * pre;

    // rgb: 24 contiguous floats per lane at ray*384 + 24*g (16B-aligned)
    const float* rbase = rgb + (size_t)ray * (N_SAMPLES * 3) + g * 24;
    float4 q0 = *reinterpret_cast<const float4*>(rbase);       // R0 G0 B0 R1
    float4 q1 = *reinterpret_cast<const float4*>(rbase + 4);   // G1 B1 R2 G2
    float4 q2 = *reinterpret_cast<const float4*>(rbase + 8);   // B2 R3 G3 B3
    float4 q3 = *reinterpret_cast<const float4*>(rbase + 12);  // R4 G4 B4 R5
    float4 q4 = *reinterpret_cast<const float4*>(rbase + 16);  // G5 B5 R6 G6
    float4 q5 = *reinterpret_cast<const float4*>(rbase + 20);  // B6 R7 G7 B7

    auto sg = [](float x) { return 1.0f / (1.0f + __expf(-x)); };

    float c0 = w0 * sg(q0.x) + w1 * sg(q0.w) + w2 * sg(q1.z) + w3 * sg(q2.y)
             + w4 * sg(q3.x) + w5 * sg(q3.w) + w6 * sg(q4.z) + w7 * sg(q5.y);
    float c1 = w0 * sg(q0.y) + w1 * sg(q1.x) + w2 * sg(q1.w) + w3 * sg(q2.z)
             + w4 * sg(q3.y) + w5 * sg(q4.x) + w6 * sg(q4.w) + w7 * sg(q5.z);
    float c2 = w0 * sg(q0.z) + w1 * sg(q1.y) + w2 * sg(q2.x) + w3 * sg(q2.w)
             + w4 * sg(q3.z) + w5 * sg(q4.y) + w6 * sg(q5.x) + w7 * sg(q5.w);
    float dd = w0 * d0.x + w1 * d0.y + w2 * d0.z + w3 * d0.w
             + w4 * d1.x + w5 * d1.y + w6 * d1.z + w7 * d1.w;

    // --- reduce across the 16-lane row: pure DPP ---
    c0 = row16_sum(c0);
    c1 = row16_sum(c1);
    c2 = row16_sum(c2);
    dd = row16_sum(dd);

    if (g == 0) {
        out_color[(size_t)ray * 3 + 0] = c0;
        out_color[(size_t)ray * 3 + 1] = c1;
        out_color[(size_t)ray * 3 + 2] = c2;
        out_depth[ray] = dd;
    }
}

extern "C" void kernel_launch(void* const* d_in, const int* in_sizes, int n_in,
                              void* d_out, int out_size, void* d_ws, size_t ws_size,
                              hipStream_t stream)
{
    const float* depth = (const float*)d_in[0];
    const float* rgb   = (const float*)d_in[1];
    const float* sigma = (const float*)d_in[2];

    const int n_rays = in_sizes[0] / N_SAMPLES;

    float* out_color = (float*)d_out;                      // [n_rays, 3]
    float* out_depth = out_color + (size_t)n_rays * 3;     // [n_rays, 1]

    const int rays_per_block = 16;  // 256 threads, 16 lanes/ray
    const int blocks = (n_rays + rays_per_block - 1) / rays_per_block;

    hipLaunchKernelGGL(volrender_kernel, dim3(blocks), dim3(256), 0, stream,
                       depth, rgb, sigma, out_color, out_depth, n_rays);
}

// Round 6
// 61.813 us; speedup vs baseline: 1.1494x; 1.1494x over previous
//
#include <hip/hip_runtime.h>

#define N_SAMPLES 128

// DPP ctrl encodings (gfx9/CDNA)
#define DPP_ROW_SHR1  0x111
#define DPP_ROW_SHR2  0x112
#define DPP_ROW_SHR4  0x114
#define DPP_ROW_SHR8  0x118
#define DPP_ROW_ROR4  0x124
#define DPP_ROW_ROR8  0x128
#define DPP_BCAST15   0x142  // broadcast lane15 of each row to the NEXT row
#define DPP_QUAD_XOR1 0xB1   // quad_perm [1,0,3,2]
#define DPP_QUAD_XOR2 0x4E   // quad_perm [2,3,0,1]

template <int CTRL, int ROWMASK>
__device__ __forceinline__ float dpp_shift_id1(float src) {
    int s = __builtin_bit_cast(int, src);
    int o = __builtin_bit_cast(int, 1.0f);
    int r = __builtin_amdgcn_update_dpp(o, s, CTRL, ROWMASK, 0xF, false);
    return __builtin_bit_cast(float, r);
}

template <int CTRL>
__device__ __forceinline__ float dpp_mov(float src) {
    int r = __builtin_amdgcn_mov_dpp(__builtin_bit_cast(int, src), CTRL, 0xF, 0xF, true);
    return __builtin_bit_cast(float, r);
}

__device__ __forceinline__ float row16_sum(float x) {
    x += dpp_mov<DPP_QUAD_XOR1>(x);
    x += dpp_mov<DPP_QUAD_XOR2>(x);
    x += dpp_mov<DPP_ROW_ROR4>(x);
    x += dpp_mov<DPP_ROW_ROR8>(x);
    return x;
}

__device__ __forceinline__ float swz_xor16(float x) {
    int r = __builtin_amdgcn_ds_swizzle(__builtin_bit_cast(int, x), 0x401F);
    return __builtin_bit_cast(float, r);
}

__global__ __launch_bounds__(256) void volrender_kernel(
    const float* __restrict__ depth,
    const float* __restrict__ rgb,
    const float* __restrict__ sigma,
    float* __restrict__ out_color,
    float* __restrict__ out_depth,
    int n_rays)
{
    // 32 lanes per ray, 4 samples per lane. 2 rays per wave, 8 rays per block.
    __shared__ float4 lds[4 * 192];   // 12 KB: per-wave 2-ray rgb staging

    const int tid   = threadIdx.x;
    const int wid   = tid >> 6;           // wave within block
    const int l64   = tid & 63;           // lane within wave
    const int llane = tid & 31;           // lane within the ray's 32-lane group
    const int sub   = (tid >> 5) & 1;     // which of the wave's 2 rays

    const int wave_ray0 = blockIdx.x * 8 + wid * 2;
    const int ray       = wave_ray0 + sub;

    // Clamped addressing so full waves can cooperate even on a tail block.
    const int cray  = (ray < n_rays) ? ray : (n_rays - 1);
    const int cwr0  = (wave_ray0 + 1 < n_rays) ? wave_ray0 : (n_rays - 2);

    const size_t base = (size_t)cray * N_SAMPLES;

    // ---- per-lane contiguous loads (1 KB per wave per instruction) ----
    float4 d = *reinterpret_cast<const float4*>(depth + base + 4 * llane);
    float4 s = *reinterpret_cast<const float4*>(sigma + base + 4 * llane);

    // ---- cooperative fully-coalesced rgb load: 3 x 1 KB contiguous ----
    const float4* rgbv = reinterpret_cast<const float4*>(rgb) + (size_t)cwr0 * 96;
    float4 v0 = rgbv[l64];
    float4 v1 = rgbv[64 + l64];
    float4 v2 = rgbv[128 + l64];

    // delta[i] = d[i+1] - d[i]; sample 127 padded with 1e10
    float dnext  = __shfl_down(d.x, 1, 32);
    float delta0 = d.y - d.x;
    float delta1 = d.z - d.y;
    float delta2 = d.w - d.z;
    float delta3 = (llane == 31) ? 1e10f : (dnext - d.w);

    const float EPS = 1e-10f;
    float e0 = __expf(-fmaxf(s.x, 0.0f) * delta0);
    float e1 = __expf(-fmaxf(s.y, 0.0f) * delta1);
    float e2 = __expf(-fmaxf(s.z, 0.0f) * delta2);
    float e3 = __expf(-fmaxf(s.w, 0.0f) * delta3);
    float a0 = 1.0f - e0, a1 = 1.0f - e1, a2 = 1.0f - e2, a3 = 1.0f - e3;
    float t0 = e0 + EPS, t1 = e1 + EPS, t2 = e2 + EPS, t3 = e3 + EPS;

    // --- 32-lane exclusive multiplicative scan of per-lane product, all DPP ---
    float rowincl = t0 * t1 * t2 * t3;
    rowincl *= dpp_shift_id1<DPP_ROW_SHR1, 0xF>(rowincl);
    rowincl *= dpp_shift_id1<DPP_ROW_SHR2, 0xF>(rowincl);
    rowincl *= dpp_shift_id1<DPP_ROW_SHR4, 0xF>(rowincl);
    rowincl *= dpp_shift_id1<DPP_ROW_SHR8, 0xF>(rowincl);  // within-row-16 inclusive
    // BCAST15 writes NEXT row (row2 <- lane31!); row_mask=0xA keeps rows 0,2 at 1.0
    float b       = dpp_shift_id1<DPP_BCAST15, 0xA>(rowincl);
    float rowexcl = dpp_shift_id1<DPP_ROW_SHR1, 0xF>(rowincl);
    float excl    = rowexcl * b;   // exact 32-lane exclusive prefix

    float w0 = a0 * excl;
    float pre1 = excl * t0;
    float w1 = a1 * pre1;
    float pre2 = pre1 * t1;
    float w2 = a2 * pre2;
    float w3 = a3 * pre2 * t2;

    // ---- stage rgb through LDS (same-wave, no barrier needed) ----
    float4* wlds = lds + wid * 192;
    wlds[l64]       = v0;
    wlds[64 + l64]  = v1;
    wlds[128 + l64] = v2;

    // per-sample layout readback: float4 index sub*96 + llane*3 (+0,1,2)
    // byte stride 48/lane -> conflict-free b128 reads
    const float4* myrgb = wlds + sub * 96 + llane * 3;
    float4 q0 = myrgb[0];   // R0 G0 B0 R1
    float4 q1 = myrgb[1];   // G1 B1 R2 G2
    float4 q2 = myrgb[2];   // B2 R3 G3 B3

    auto sg = [](float x) { return 1.0f / (1.0f + __expf(-x)); };

    float c0 = w0 * sg(q0.x) + w1 * sg(q0.w) + w2 * sg(q1.z) + w3 * sg(q2.y);
    float c1 = w0 * sg(q0.y) + w1 * sg(q1.x) + w2 * sg(q1.w) + w3 * sg(q2.z);
    float c2 = w0 * sg(q0.z) + w1 * sg(q1.y) + w2 * sg(q2.x) + w3 * sg(q2.w);
    float dd = w0 * d.x + w1 * d.y + w2 * d.z + w3 * d.w;

    // --- reduce across the 32-lane group: DPP row sum + one xor16 swizzle ---
    c0 = row16_sum(c0); c0 += swz_xor16(c0);
    c1 = row16_sum(c1); c1 += swz_xor16(c1);
    c2 = row16_sum(c2); c2 += swz_xor16(c2);
    dd = row16_sum(dd); dd += swz_xor16(dd);

    if (llane == 0 && ray < n_rays) {
        out_color[(size_t)ray * 3 + 0] = c0;
        out_color[(size_t)ray * 3 + 1] = c1;
        out_color[(size_t)ray * 3 + 2] = c2;
        out_depth[ray] = dd;
    }
}

extern "C" void kernel_launch(void* const* d_in, const int* in_sizes, int n_in,
                              void* d_out, int out_size, void* d_ws, size_t ws_size,
                              hipStream_t stream)
{
    const float* depth = (const float*)d_in[0];
    const float* rgb   = (const float*)d_in[1];
    const float* sigma = (const float*)d_in[2];

    const int n_rays = in_sizes[0] / N_SAMPLES;

    float* out_color = (float*)d_out;                      // [n_rays, 3]
    float* out_depth = out_color + (size_t)n_rays * 3;     // [n_rays, 1]

    const int rays_per_block = 8;  // 256 threads, 32 lanes/ray
    const int blocks = (n_rays + rays_per_block - 1) / rays_per_block;

    hipLaunchKernelGGL(volrender_kernel, dim3(blocks), dim3(256), 0, stream,
                       depth, rgb, sigma, out_color, out_depth, n_rays);
}